// Round 2
// baseline (306.042 us; speedup 1.0000x reference)
//
#include <hip/hip_runtime.h>
#include <cmath>

// FusionLoss = ms_ssim(fus,ir)+ms_ssim(fus,vi) + l1(max(map_ir,map_vi),fus)
//            + 10*mean(|max(|lap ir|,|lap vi|) - |lap fus||)
// Inputs: im_fus, im_ir, im_vi, map_ir, map_vi  each [32,1,512,512] fp32.
// d_ws layout: acc[0]=ssim_sum (both maps), acc[1]=l1_sum, acc[2]=grad_sum.

struct GaussW { float w[11]; };

#define SSIM_C1 1.0e-4f
#define SSIM_C2 9.0e-4f

__global__ void zero_kernel(float* __restrict__ acc) {
    if (threadIdx.x < 8) acc[threadIdx.x] = 0.f;
}

// ---------------- Kernel A: fused double SSIM (separable 11x11 gaussian) ----
// Grid: (2 col strips of 256, 8 row strips of 64, 32 batch). Block: 256.
// Each thread owns one output column; sweeps input rows; horizontal gaussian
// sums from an LDS row ring; vertical gaussian via an 11-slot register ring
// (statically indexed through the unrolled phase loop).
// Ring discipline: slot (o mod 11) is OVERWRITTEN (not +=) by the k=0
// contribution when output row o starts at input row r=o — this wipes the
// phantom (o<0) garbage that rows r=0..9 deposit with k>r weights. That
// phantom contamination was the round-1 0.39 absmax bug.
__global__ __launch_bounds__(256, 2)
void ssim_kernel(const float* __restrict__ fus, const float* __restrict__ irp,
                 const float* __restrict__ vip, float* __restrict__ accum,
                 GaussW gw)
{
    const int b   = blockIdx.z;
    const int r0  = blockIdx.y * 64;
    const int c0  = blockIdx.x * 256;
    const int tid = threadIdx.x;
    const int out_rows = min(64, 502 - r0);
    const int in_rows  = out_rows + 10;

    const size_t ib = (size_t)b * 512 * 512;
    const float* __restrict__ Fp = fus + ib;
    const float* __restrict__ Ip = irp + ib;
    const float* __restrict__ Vp = vip + ib;

    __shared__ float srow[2][3][268];   // double-buffered input row strip

    float w[11];
#pragma unroll
    for (int k = 0; k < 11; ++k) w[k] = gw.w[k];

    float acc[11][8];                    // register ring: 11 in-flight rows x 8 quantities
#pragma unroll
    for (int s = 0; s < 11; ++s)
#pragma unroll
        for (int q = 0; q < 8; ++q) acc[s][q] = 0.f;

    float lssim = 0.f;
    const bool col_ok   = (c0 + tid) <= 501;       // valid output column
    const bool extra    = (tid < 10);              // loads the 10-col halo
    const int  col2     = c0 + 256 + tid;
    const bool extra_ok = extra && (col2 < 512);

    // prefetch input row 0
    float rf, rg, rv, rf2 = 0.f, rg2 = 0.f, rv2 = 0.f;
    {
        const size_t base = (size_t)r0 * 512 + c0 + tid;
        rf = Fp[base]; rg = Ip[base]; rv = Vp[base];
        if (extra_ok) {
            const size_t b2 = (size_t)r0 * 512 + col2;
            rf2 = Fp[b2]; rg2 = Ip[b2]; rv2 = Vp[b2];
        }
    }

#pragma unroll 1
    for (int rb = 0; rb < 74; rb += 11) {
#pragma unroll
        for (int p = 0; p < 11; ++p) {
            const int r = rb + p;                 // input row within strip
            if (r < in_rows) {                    // block-uniform guard
                const int buf = r & 1;
                // stage row r into LDS
                srow[buf][0][tid] = rf;
                srow[buf][1][tid] = rg;
                srow[buf][2][tid] = rv;
                if (extra) {
                    srow[buf][0][256 + tid] = rf2;
                    srow[buf][1][256 + tid] = rg2;
                    srow[buf][2][256 + tid] = rv2;
                }
                // prefetch row r+1 (latency hides under compute below)
                if (r + 1 < in_rows) {
                    const size_t base = (size_t)(r0 + r + 1) * 512 + c0 + tid;
                    rf = Fp[base]; rg = Ip[base]; rv = Vp[base];
                    if (extra_ok) {
                        const size_t b2 = (size_t)(r0 + r + 1) * 512 + col2;
                        rf2 = Fp[b2]; rg2 = Ip[b2]; rv2 = Vp[b2];
                    }
                }
                __syncthreads();   // writes(r) -> reads(r); also orders reads(r-1) vs writes(r+1)

                // horizontal gaussian sums for the 8 quantities
                float hf=0.f,hi=0.f,hv=0.f,hff=0.f,hii=0.f,hvv=0.f,hfi=0.f,hfv=0.f;
#pragma unroll
                for (int k = 0; k < 11; ++k) {
                    const float F = srow[buf][0][tid + k];
                    const float I = srow[buf][1][tid + k];
                    const float V = srow[buf][2][tid + k];
                    const float t = w[k];
                    const float tF = t * F, tI = t * I, tV = t * V;
                    hf += tF; hi += tI; hv += tV;
                    hff = fmaf(tF, F, hff);
                    hii = fmaf(tI, I, hii);
                    hvv = fmaf(tV, V, hvv);
                    hfi = fmaf(tF, I, hfi);
                    hfv = fmaf(tF, V, hfv);
                }
                // vertical ring: k=0 OVERWRITES slot p (output row r begins;
                // wipes phantom/finalized occupant), k>=1 accumulates.
                acc[p][0] = w[0] * hf;
                acc[p][1] = w[0] * hi;
                acc[p][2] = w[0] * hv;
                acc[p][3] = w[0] * hff;
                acc[p][4] = w[0] * hii;
                acc[p][5] = w[0] * hvv;
                acc[p][6] = w[0] * hfi;
                acc[p][7] = w[0] * hfv;
#pragma unroll
                for (int k = 1; k < 11; ++k) {
                    const int s = (p - k + 11) % 11;   // compile-time
                    const float t = w[k];
                    acc[s][0] = fmaf(t, hf,  acc[s][0]);
                    acc[s][1] = fmaf(t, hi,  acc[s][1]);
                    acc[s][2] = fmaf(t, hv,  acc[s][2]);
                    acc[s][3] = fmaf(t, hff, acc[s][3]);
                    acc[s][4] = fmaf(t, hii, acc[s][4]);
                    acc[s][5] = fmaf(t, hvv, acc[s][5]);
                    acc[s][6] = fmaf(t, hfv, acc[s][6]);
                    acc[s][7] = fmaf(t, hfv, acc[s][7]);
                }
                // finalize output row r-10 (its slot just got its k=10 term)
                if (r >= 10) {
                    const int s = (p + 1) % 11;        // compile-time
                    const float mu1 = acc[s][0], mu2 = acc[s][1], mu3 = acc[s][2];
                    const float eff = acc[s][3], eii = acc[s][4], evv = acc[s][5];
                    const float efi = acc[s][6], efv = acc[s][7];
                    const float mu1sq = mu1*mu1, mu2sq = mu2*mu2, mu3sq = mu3*mu3;
                    const float mu12 = mu1*mu2, mu13 = mu1*mu3;
                    const float sf  = eff - mu1sq;
                    const float si  = eii - mu2sq;
                    const float sv  = evv - mu3sq;
                    const float s12 = efi - mu12;
                    const float s13 = efv - mu13;
                    const float n1 = (2.f*mu12 + SSIM_C1) * (2.f*s12 + SSIM_C2);
                    const float d1 = (mu1sq + mu2sq + SSIM_C1) * (sf + si + SSIM_C2);
                    const float n2 = (2.f*mu13 + SSIM_C1) * (2.f*s13 + SSIM_C2);
                    const float d2 = (mu1sq + mu3sq + SSIM_C1) * (sf + sv + SSIM_C2);
                    if (col_ok) lssim += n1/d1 + n2/d2;
                }
            }
        }
    }

    // block reduction -> one atomic
#pragma unroll
    for (int off = 32; off > 0; off >>= 1)
        lssim += __shfl_down(lssim, off);
    __shared__ float red[4];
    if ((tid & 63) == 0) red[tid >> 6] = lssim;
    __syncthreads();
    if (tid == 0) atomicAdd(accum, red[0] + red[1] + red[2] + red[3]);
}

// ---------------- Kernel B: L1 + laplacian grad loss ------------------------
__device__ inline float4 lap3x3(const float* __restrict__ rm,
                                const float* __restrict__ rc,
                                const float* __restrict__ rp,
                                int x0, int xl, int xr, float4& center)
{
    float4 a = *(const float4*)(rm + x0);
    float4 b = *(const float4*)(rc + x0);
    float4 c = *(const float4*)(rp + x0);
    const float aL = rm[xl], bL = rc[xl], cL = rp[xl];
    const float aR = rm[xr], bR = rc[xr], cR = rp[xr];
    const float s0 = aL + bL + cL;
    const float s1 = a.x + b.x + c.x;
    const float s2 = a.y + b.y + c.y;
    const float s3 = a.z + b.z + c.z;
    const float s4 = a.w + b.w + c.w;
    const float s5 = aR + bR + cR;
    center = b;
    float4 l;
    l.x = (s0 + s1 + s2 - 9.f*b.x) * 0.0625f;
    l.y = (s1 + s2 + s3 - 9.f*b.y) * 0.0625f;
    l.z = (s2 + s3 + s4 - 9.f*b.z) * 0.0625f;
    l.w = (s3 + s4 + s5 - 9.f*b.w) * 0.0625f;
    return l;
}

__global__ __launch_bounds__(256, 4)
void lapl1_kernel(const float* __restrict__ fus, const float* __restrict__ irp,
                  const float* __restrict__ vip, const float* __restrict__ mir,
                  const float* __restrict__ mvi, float* __restrict__ accum)
{
    const int b   = blockIdx.y;
    const int tid = threadIdx.x;
    const int y   = blockIdx.x * 2 + (tid >> 7);   // 2 rows per block
    const int xq  = tid & 127;
    const int x0  = xq * 4;
    const size_t ib = (size_t)b * 512 * 512;

    const int ym = (y == 0)   ? 1   : y - 1;       // reflect padding
    const int yp = (y == 511) ? 510 : y + 1;
    const int xl = (x0 == 0)        ? 1   : x0 - 1;
    const int xr = (x0 + 4 == 512)  ? 510 : x0 + 4;

    const float* Fb = fus + ib;
    const float* Ib = irp + ib;
    const float* Vb = vip + ib;

    float4 cf, ci, cv;
    const float4 lf = lap3x3(Fb + (size_t)ym*512, Fb + (size_t)y*512, Fb + (size_t)yp*512, x0, xl, xr, cf);
    const float4 li = lap3x3(Ib + (size_t)ym*512, Ib + (size_t)y*512, Ib + (size_t)yp*512, x0, xl, xr, ci);
    const float4 lv = lap3x3(Vb + (size_t)ym*512, Vb + (size_t)y*512, Vb + (size_t)yp*512, x0, xl, xr, cv);

    const float4 m1 = *(const float4*)(mir + ib + (size_t)y*512 + x0);
    const float4 m2 = *(const float4*)(mvi + ib + (size_t)y*512 + x0);

    float l1s =
        fabsf(fmaxf(m1.x, m2.x) - cf.x) + fabsf(fmaxf(m1.y, m2.y) - cf.y) +
        fabsf(fmaxf(m1.z, m2.z) - cf.z) + fabsf(fmaxf(m1.w, m2.w) - cf.w);

    float grs =
        fabsf(fmaxf(fabsf(li.x), fabsf(lv.x)) - fabsf(lf.x)) +
        fabsf(fmaxf(fabsf(li.y), fabsf(lv.y)) - fabsf(lf.y)) +
        fabsf(fmaxf(fabsf(li.z), fabsf(lv.z)) - fabsf(lf.z)) +
        fabsf(fmaxf(fabsf(li.w), fabsf(lv.w)) - fabsf(lf.w));

#pragma unroll
    for (int off = 32; off > 0; off >>= 1) {
        l1s += __shfl_down(l1s, off);
        grs += __shfl_down(grs, off);
    }
    __shared__ float red[8];
    if ((tid & 63) == 0) { red[tid >> 6] = l1s; red[4 + (tid >> 6)] = grs; }
    __syncthreads();
    if (tid == 0) {
        atomicAdd(accum + 1, red[0] + red[1] + red[2] + red[3]);
        atomicAdd(accum + 2, red[4] + red[5] + red[6] + red[7]);
    }
}

// ---------------- final combine --------------------------------------------
__global__ void final_kernel(const float* __restrict__ acc, float* __restrict__ out)
{
    // ms_ssim_loss = 2 - ssim_sum/Nvalid ; l1 = l1_sum/N ; grad = grad_sum/N
    const float ms = 2.f - acc[0] / 8064128.f;     // 32*502*502
    const float l1 = acc[1] / 8388608.f;           // 32*512*512
    const float gr = acc[2] / 8388608.f;
    out[0] = ms + l1 + 10.f * gr;
}

extern "C" void kernel_launch(void* const* d_in, const int* in_sizes, int n_in,
                              void* d_out, int out_size, void* d_ws, size_t ws_size,
                              hipStream_t stream)
{
    const float* fus = (const float*)d_in[0];
    const float* irp = (const float*)d_in[1];
    const float* vip = (const float*)d_in[2];
    const float* mir = (const float*)d_in[3];
    const float* mvi = (const float*)d_in[4];
    float* out = (float*)d_out;
    float* acc = (float*)d_ws;

    // gaussian window (matches np: f64 normalize, cast to f32)
    GaussW gw;
    double g[11], s = 0.0;
    for (int i = 0; i < 11; ++i) {
        const double d = (double)i - 5.0;
        g[i] = std::exp(-(d * d) / (2.0 * 1.5 * 1.5));
        s += g[i];
    }
    for (int i = 0; i < 11; ++i) gw.w[i] = (float)(g[i] / s);

    zero_kernel<<<1, 64, 0, stream>>>(acc);
    ssim_kernel<<<dim3(2, 8, 32), 256, 0, stream>>>(fus, irp, vip, acc, gw);
    lapl1_kernel<<<dim3(256, 32), 256, 0, stream>>>(fus, irp, vip, mir, mvi, acc);
    final_kernel<<<1, 1, 0, stream>>>(acc, out);
}

// Round 3
// 125.919 us; speedup vs baseline: 2.4305x; 2.4305x over previous
//
#include <hip/hip_runtime.h>
#include <cmath>

// FusionLoss = ms_ssim(fus,ir)+ms_ssim(fus,vi) + l1(max(map_ir,map_vi),fus)
//            + 10*mean(|max(|lap ir|,|lap vi|) - |lap fus||)
// Inputs: im_fus, im_ir, im_vi, map_ir, map_vi  each [32,1,512,512] fp32.
//
// d_ws layout (floats): [0..512)    ssim partials   (512 ssim blocks)
//                       [512..2560) l1 partials     (2048 lapl1 blocks)
//                       [2560..4608) grad partials  (2048 lapl1 blocks)
// No atomics anywhere: round-2 counters showed 8192 same-address device
// atomics serialized as 64B memory-side round-trips (WRITE_SIZE==8192*64B,
// 215us at 5% VALUBusy). Partials + tree reduce instead.

struct GaussW { float w[11]; };

#define SSIM_C1 1.0e-4f
#define SSIM_C2 9.0e-4f

// ---------------- Kernel A: fused double SSIM (separable 11x11 gaussian) ----
// Grid: (2 col strips of 256, 8 row strips of 64, 32 batch). Block: 256.
// Each thread owns one output column; sweeps input rows; horizontal gaussian
// sums from an LDS row ring; vertical gaussian via an 11-slot register ring
// (statically indexed through the unrolled phase loop). Slot (o mod 11) is
// OVERWRITTEN by the k=0 term when output row o begins (wipes phantom o<0
// garbage deposited during the first 10 rows).
__global__ __launch_bounds__(256, 2)
void ssim_kernel(const float* __restrict__ fus, const float* __restrict__ irp,
                 const float* __restrict__ vip, float* __restrict__ part,
                 GaussW gw)
{
    const int b   = blockIdx.z;
    const int r0  = blockIdx.y * 64;
    const int c0  = blockIdx.x * 256;
    const int tid = threadIdx.x;
    const int out_rows = min(64, 502 - r0);
    const int in_rows  = out_rows + 10;

    const size_t ib = (size_t)b * 512 * 512;
    const float* __restrict__ Fp = fus + ib;
    const float* __restrict__ Ip = irp + ib;
    const float* __restrict__ Vp = vip + ib;

    __shared__ float srow[2][3][268];   // double-buffered input row strip

    float w[11];
#pragma unroll
    for (int k = 0; k < 11; ++k) w[k] = gw.w[k];

    float acc[11][8];                    // register ring: 11 in-flight rows x 8 quantities
#pragma unroll
    for (int s = 0; s < 11; ++s)
#pragma unroll
        for (int q = 0; q < 8; ++q) acc[s][q] = 0.f;

    float lssim = 0.f;
    const bool col_ok   = (c0 + tid) <= 501;       // valid output column
    const bool extra    = (tid < 10);              // loads the 10-col halo
    const int  col2     = c0 + 256 + tid;
    const bool extra_ok = extra && (col2 < 512);

    // prefetch input row 0
    float rf, rg, rv, rf2 = 0.f, rg2 = 0.f, rv2 = 0.f;
    {
        const size_t base = (size_t)r0 * 512 + c0 + tid;
        rf = Fp[base]; rg = Ip[base]; rv = Vp[base];
        if (extra_ok) {
            const size_t b2 = (size_t)r0 * 512 + col2;
            rf2 = Fp[b2]; rg2 = Ip[b2]; rv2 = Vp[b2];
        }
    }

#pragma unroll 1
    for (int rb = 0; rb < 74; rb += 11) {
#pragma unroll
        for (int p = 0; p < 11; ++p) {
            const int r = rb + p;                 // input row within strip
            if (r < in_rows) {                    // block-uniform guard
                const int buf = r & 1;
                // stage row r into LDS
                srow[buf][0][tid] = rf;
                srow[buf][1][tid] = rg;
                srow[buf][2][tid] = rv;
                if (extra) {
                    srow[buf][0][256 + tid] = rf2;
                    srow[buf][1][256 + tid] = rg2;
                    srow[buf][2][256 + tid] = rv2;
                }
                // prefetch row r+1 (latency hides under compute below)
                if (r + 1 < in_rows) {
                    const size_t base = (size_t)(r0 + r + 1) * 512 + c0 + tid;
                    rf = Fp[base]; rg = Ip[base]; rv = Vp[base];
                    if (extra_ok) {
                        const size_t b2 = (size_t)(r0 + r + 1) * 512 + col2;
                        rf2 = Fp[b2]; rg2 = Ip[b2]; rv2 = Vp[b2];
                    }
                }
                __syncthreads();   // writes(r) -> reads(r); also orders reads(r-1) vs writes(r+1)

                // horizontal gaussian sums for the 8 quantities
                float hf=0.f,hi=0.f,hv=0.f,hff=0.f,hii=0.f,hvv=0.f,hfi=0.f,hfv=0.f;
#pragma unroll
                for (int k = 0; k < 11; ++k) {
                    const float F = srow[buf][0][tid + k];
                    const float I = srow[buf][1][tid + k];
                    const float V = srow[buf][2][tid + k];
                    const float t = w[k];
                    const float tF = t * F, tI = t * I, tV = t * V;
                    hf += tF; hi += tI; hv += tV;
                    hff = fmaf(tF, F, hff);
                    hii = fmaf(tI, I, hii);
                    hvv = fmaf(tV, V, hvv);
                    hfi = fmaf(tF, I, hfi);
                    hfv = fmaf(tF, V, hfv);
                }
                // vertical ring: k=0 OVERWRITES slot p, k>=1 accumulates.
                acc[p][0] = w[0] * hf;
                acc[p][1] = w[0] * hi;
                acc[p][2] = w[0] * hv;
                acc[p][3] = w[0] * hff;
                acc[p][4] = w[0] * hii;
                acc[p][5] = w[0] * hvv;
                acc[p][6] = w[0] * hfi;
                acc[p][7] = w[0] * hfv;
#pragma unroll
                for (int k = 1; k < 11; ++k) {
                    const int s = (p - k + 11) % 11;   // compile-time
                    const float t = w[k];
                    acc[s][0] = fmaf(t, hf,  acc[s][0]);
                    acc[s][1] = fmaf(t, hi,  acc[s][1]);
                    acc[s][2] = fmaf(t, hv,  acc[s][2]);
                    acc[s][3] = fmaf(t, hff, acc[s][3]);
                    acc[s][4] = fmaf(t, hii, acc[s][4]);
                    acc[s][5] = fmaf(t, hvv, acc[s][5]);
                    acc[s][6] = fmaf(t, hfi, acc[s][6]);
                    acc[s][7] = fmaf(t, hfv, acc[s][7]);
                }
                // finalize output row r-10 (its slot just got its k=10 term)
                if (r >= 10) {
                    const int s = (p + 1) % 11;        // compile-time
                    const float mu1 = acc[s][0], mu2 = acc[s][1], mu3 = acc[s][2];
                    const float eff = acc[s][3], eii = acc[s][4], evv = acc[s][5];
                    const float efi = acc[s][6], efv = acc[s][7];
                    const float mu1sq = mu1*mu1, mu2sq = mu2*mu2, mu3sq = mu3*mu3;
                    const float mu12 = mu1*mu2, mu13 = mu1*mu3;
                    const float sf  = eff - mu1sq;
                    const float si  = eii - mu2sq;
                    const float sv  = evv - mu3sq;
                    const float s12 = efi - mu12;
                    const float s13 = efv - mu13;
                    const float n1 = (2.f*mu12 + SSIM_C1) * (2.f*s12 + SSIM_C2);
                    const float d1 = (mu1sq + mu2sq + SSIM_C1) * (sf + si + SSIM_C2);
                    const float n2 = (2.f*mu13 + SSIM_C1) * (2.f*s13 + SSIM_C2);
                    const float d2 = (mu1sq + mu3sq + SSIM_C1) * (sf + sv + SSIM_C2);
                    if (col_ok) lssim += n1/d1 + n2/d2;
                }
            }
        }
    }

    // block reduction -> one partial-sum write (NO atomic)
#pragma unroll
    for (int off = 32; off > 0; off >>= 1)
        lssim += __shfl_down(lssim, off);
    __shared__ float red[4];
    if ((tid & 63) == 0) red[tid >> 6] = lssim;
    __syncthreads();
    if (tid == 0) {
        const int blk = blockIdx.x + 2 * (blockIdx.y + 8 * blockIdx.z); // 0..511
        part[blk] = red[0] + red[1] + red[2] + red[3];
    }
}

// ---------------- Kernel B: L1 + laplacian grad loss ------------------------
__device__ inline float4 lap3x3(const float* __restrict__ rm,
                                const float* __restrict__ rc,
                                const float* __restrict__ rp,
                                int x0, int xl, int xr, float4& center)
{
    float4 a = *(const float4*)(rm + x0);
    float4 b = *(const float4*)(rc + x0);
    float4 c = *(const float4*)(rp + x0);
    const float aL = rm[xl], bL = rc[xl], cL = rp[xl];
    const float aR = rm[xr], bR = rc[xr], cR = rp[xr];
    const float s0 = aL + bL + cL;
    const float s1 = a.x + b.x + c.x;
    const float s2 = a.y + b.y + c.y;
    const float s3 = a.z + b.z + c.z;
    const float s4 = a.w + b.w + c.w;
    const float s5 = aR + bR + cR;
    center = b;
    float4 l;
    l.x = (s0 + s1 + s2 - 9.f*b.x) * 0.0625f;
    l.y = (s1 + s2 + s3 - 9.f*b.y) * 0.0625f;
    l.z = (s2 + s3 + s4 - 9.f*b.z) * 0.0625f;
    l.w = (s3 + s4 + s5 - 9.f*b.w) * 0.0625f;
    return l;
}

// Grid: dim3(64, 32) = 2048 blocks; each block covers 8 rows of one batch
// image (4 iterations x 2 rows). Partial sums to d_ws, no atomics.
__global__ __launch_bounds__(256, 4)
void lapl1_kernel(const float* __restrict__ fus, const float* __restrict__ irp,
                  const float* __restrict__ vip, const float* __restrict__ mir,
                  const float* __restrict__ mvi,
                  float* __restrict__ part_l1, float* __restrict__ part_gr)
{
    const int b   = blockIdx.y;
    const int tid = threadIdx.x;
    const int xq  = tid & 127;
    const int x0  = xq * 4;
    const size_t ib = (size_t)b * 512 * 512;

    const int xl = (x0 == 0)        ? 1   : x0 - 1;   // reflect padding (x)
    const int xr = (x0 + 4 == 512)  ? 510 : x0 + 4;

    const float* Fb = fus + ib;
    const float* Ib = irp + ib;
    const float* Vb = vip + ib;

    float l1s = 0.f, grs = 0.f;

#pragma unroll
    for (int it = 0; it < 4; ++it) {
        const int y  = blockIdx.x * 8 + it * 2 + (tid >> 7);
        const int ym = (y == 0)   ? 1   : y - 1;       // reflect padding (y)
        const int yp = (y == 511) ? 510 : y + 1;

        float4 cf, ci, cv;
        const float4 lf = lap3x3(Fb + (size_t)ym*512, Fb + (size_t)y*512, Fb + (size_t)yp*512, x0, xl, xr, cf);
        const float4 li = lap3x3(Ib + (size_t)ym*512, Ib + (size_t)y*512, Ib + (size_t)yp*512, x0, xl, xr, ci);
        const float4 lv = lap3x3(Vb + (size_t)ym*512, Vb + (size_t)y*512, Vb + (size_t)yp*512, x0, xl, xr, cv);

        const float4 m1 = *(const float4*)(mir + ib + (size_t)y*512 + x0);
        const float4 m2 = *(const float4*)(mvi + ib + (size_t)y*512 + x0);

        l1s += fabsf(fmaxf(m1.x, m2.x) - cf.x) + fabsf(fmaxf(m1.y, m2.y) - cf.y)
             + fabsf(fmaxf(m1.z, m2.z) - cf.z) + fabsf(fmaxf(m1.w, m2.w) - cf.w);

        grs += fabsf(fmaxf(fabsf(li.x), fabsf(lv.x)) - fabsf(lf.x))
             + fabsf(fmaxf(fabsf(li.y), fabsf(lv.y)) - fabsf(lf.y))
             + fabsf(fmaxf(fabsf(li.z), fabsf(lv.z)) - fabsf(lf.z))
             + fabsf(fmaxf(fabsf(li.w), fabsf(lv.w)) - fabsf(lf.w));
    }

#pragma unroll
    for (int off = 32; off > 0; off >>= 1) {
        l1s += __shfl_down(l1s, off);
        grs += __shfl_down(grs, off);
    }
    __shared__ float red[8];
    if ((tid & 63) == 0) { red[tid >> 6] = l1s; red[4 + (tid >> 6)] = grs; }
    __syncthreads();
    if (tid == 0) {
        const int blk = blockIdx.x + 64 * blockIdx.y;  // 0..2047
        part_l1[blk] = red[0] + red[1] + red[2] + red[3];
        part_gr[blk] = red[4] + red[5] + red[6] + red[7];
    }
}

// ---------------- final combine: reduce all partials ------------------------
__global__ void final_kernel(const float* __restrict__ ws, float* __restrict__ out)
{
    const int tid = threadIdx.x;
    float s0 = 0.f, s1 = 0.f, s2 = 0.f;
#pragma unroll
    for (int i = tid; i < 512; i += 256) s0 += ws[i];
#pragma unroll
    for (int i = tid; i < 2048; i += 256) {
        s1 += ws[512 + i];
        s2 += ws[2560 + i];
    }
#pragma unroll
    for (int off = 32; off > 0; off >>= 1) {
        s0 += __shfl_down(s0, off);
        s1 += __shfl_down(s1, off);
        s2 += __shfl_down(s2, off);
    }
    __shared__ float red[12];
    if ((tid & 63) == 0) {
        red[tid >> 6] = s0; red[4 + (tid >> 6)] = s1; red[8 + (tid >> 6)] = s2;
    }
    __syncthreads();
    if (tid == 0) {
        const float ssim_sum = red[0] + red[1] + red[2] + red[3];
        const float l1_sum   = red[4] + red[5] + red[6] + red[7];
        const float gr_sum   = red[8] + red[9] + red[10] + red[11];
        const float ms = 2.f - ssim_sum / 8064128.f;   // 32*502*502
        const float l1 = l1_sum / 8388608.f;           // 32*512*512
        const float gr = gr_sum / 8388608.f;
        out[0] = ms + l1 + 10.f * gr;
    }
}

extern "C" void kernel_launch(void* const* d_in, const int* in_sizes, int n_in,
                              void* d_out, int out_size, void* d_ws, size_t ws_size,
                              hipStream_t stream)
{
    const float* fus = (const float*)d_in[0];
    const float* irp = (const float*)d_in[1];
    const float* vip = (const float*)d_in[2];
    const float* mir = (const float*)d_in[3];
    const float* mvi = (const float*)d_in[4];
    float* out = (float*)d_out;
    float* ws  = (float*)d_ws;

    // gaussian window (matches np: f64 normalize, cast to f32)
    GaussW gw;
    double g[11], s = 0.0;
    for (int i = 0; i < 11; ++i) {
        const double d = (double)i - 5.0;
        g[i] = std::exp(-(d * d) / (2.0 * 1.5 * 1.5));
        s += g[i];
    }
    for (int i = 0; i < 11; ++i) gw.w[i] = (float)(g[i] / s);

    ssim_kernel<<<dim3(2, 8, 32), 256, 0, stream>>>(fus, irp, vip, ws, gw);
    lapl1_kernel<<<dim3(64, 32), 256, 0, stream>>>(fus, irp, vip, mir, mvi,
                                                   ws + 512, ws + 2560);
    final_kernel<<<1, 256, 0, stream>>>(ws, out);
}

// Round 4
// 121.375 us; speedup vs baseline: 2.5215x; 1.0374x over previous
//
#include <hip/hip_runtime.h>
#include <cmath>

// FusionLoss = ms_ssim(fus,ir)+ms_ssim(fus,vi) + l1(max(map_ir,map_vi),fus)
//            + 10*mean(|max(|lap ir|,|lap vi|) - |lap fus||)
// Inputs: im_fus, im_ir, im_vi, map_ir, map_vi  each [32,1,512,512] fp32.
//
// d_ws layout (floats): [0..1024)    ssim partials  (1024 ssim blocks)
//                       [1024..3072) l1 partials    (2048 lapl1 blocks)
//                       [3072..5120) grad partials  (2048 lapl1 blocks)
// No atomics (round-2 lesson: same-address device atomics serialize at
// ~25ns each). Round-4 change: barrier-free wave-private SSIM strips +
// 4x grid for occupancy (round-3 counters: Occupancy 17.9%, VALUBusy 62%).

struct GaussW { float w[11]; };

#define SSIM_C1 1.0e-4f
#define SSIM_C2 9.0e-4f

// ---------------- Kernel A: fused double SSIM (separable 11x11 gaussian) ----
// Grid: (2 col blocks of 256, 16 row strips of 32, 32 batch) = 1024 blocks.
// Each 256-thread block = 4 INDEPENDENT waves; wave wv owns 64 columns
// (c0+wv*64) and a private single-buffered LDS row strip. No __syncthreads
// in the main loop: within a wave the DS pipe is in-order, so the
// stage-row -> read-window dependency is program-order-safe.
// Vertical gaussian via an 11-slot register ring; slot (o mod 11) is
// OVERWRITTEN by the k=0 term when output row o begins (wipes phantom
// o<0 garbage from the first 10 warm-up rows).
__global__ __launch_bounds__(256, 3)
void ssim_kernel(const float* __restrict__ fus, const float* __restrict__ irp,
                 const float* __restrict__ vip, float* __restrict__ part,
                 GaussW gw)
{
    const int b    = blockIdx.z;
    const int r0   = blockIdx.y * 32;
    const int tid  = threadIdx.x;
    const int wv   = tid >> 6;          // wave 0..3
    const int lane = tid & 63;
    const int c0   = blockIdx.x * 256 + wv * 64;   // wave's column base
    const int out_rows = min(32, 502 - r0);
    const int in_rows  = out_rows + 10;

    const size_t ib = (size_t)b * 512 * 512;
    const float* __restrict__ Fp = fus + ib;
    const float* __restrict__ Ip = irp + ib;
    const float* __restrict__ Vp = vip + ib;

    __shared__ float srow[4][3][80];    // wave-private, single-buffered

    float w6[6];                        // gaussian is symmetric: w[k]=w[10-k]
#pragma unroll
    for (int k = 0; k < 6; ++k) w6[k] = gw.w[k];

    float acc[11][8];                   // register ring: 11 rows x 8 quantities
#pragma unroll
    for (int s = 0; s < 11; ++s)
#pragma unroll
        for (int q = 0; q < 8; ++q) acc[s][q] = 0.f;

    float lssim = 0.f;
    const int  col      = c0 + lane;
    const bool col_ok   = col <= 501;             // valid output column
    const bool extra    = lane < 10;              // loads the 10-col halo
    const int  col2     = c0 + 64 + lane;
    const bool extra_ok = extra && (col2 < 512);

    // prefetch input row 0
    float rf, rg, rv, rf2 = 0.f, rg2 = 0.f, rv2 = 0.f;
    {
        const size_t base = (size_t)r0 * 512 + col;
        rf = Fp[base]; rg = Ip[base]; rv = Vp[base];
        if (extra_ok) {
            const size_t b2 = (size_t)r0 * 512 + col2;
            rf2 = Fp[b2]; rg2 = Ip[b2]; rv2 = Vp[b2];
        }
    }

#pragma unroll 1
    for (int rb = 0; rb < 44; rb += 11) {
#pragma unroll
        for (int p = 0; p < 11; ++p) {
            const int r = rb + p;                 // input row within strip
            if (r < in_rows) {                    // wave-uniform guard
                // stage row r into this wave's LDS strip
                srow[wv][0][lane] = rf;
                srow[wv][1][lane] = rg;
                srow[wv][2][lane] = rv;
                if (extra) {
                    srow[wv][0][64 + lane] = rf2;
                    srow[wv][1][64 + lane] = rg2;
                    srow[wv][2][64 + lane] = rv2;
                }
                // prefetch row r+1 (hides under compute below)
                if (r + 1 < in_rows) {
                    const size_t base = (size_t)(r0 + r + 1) * 512 + col;
                    rf = Fp[base]; rg = Ip[base]; rv = Vp[base];
                    if (extra_ok) {
                        const size_t b2 = (size_t)(r0 + r + 1) * 512 + col2;
                        rf2 = Fp[b2]; rg2 = Ip[b2]; rv2 = Vp[b2];
                    }
                }
                // NO __syncthreads: wave-private LDS + in-order DS pipe.

                // horizontal gaussian sums for the 8 quantities
                float hf=0.f,hi=0.f,hv=0.f,hff=0.f,hii=0.f,hvv=0.f,hfi=0.f,hfv=0.f;
#pragma unroll
                for (int k = 0; k < 11; ++k) {
                    const float t = w6[k < 6 ? k : 10 - k];
                    const float F = srow[wv][0][lane + k];
                    const float I = srow[wv][1][lane + k];
                    const float V = srow[wv][2][lane + k];
                    const float tF = t * F, tI = t * I, tV = t * V;
                    hf += tF; hi += tI; hv += tV;
                    hff = fmaf(tF, F, hff);
                    hii = fmaf(tI, I, hii);
                    hvv = fmaf(tV, V, hvv);
                    hfi = fmaf(tF, I, hfi);
                    hfv = fmaf(tF, V, hfv);
                }
                // vertical ring: k=0 OVERWRITES slot p, k>=1 accumulates.
                acc[p][0] = w6[0] * hf;
                acc[p][1] = w6[0] * hi;
                acc[p][2] = w6[0] * hv;
                acc[p][3] = w6[0] * hff;
                acc[p][4] = w6[0] * hii;
                acc[p][5] = w6[0] * hvv;
                acc[p][6] = w6[0] * hfi;
                acc[p][7] = w6[0] * hfv;
#pragma unroll
                for (int k = 1; k < 11; ++k) {
                    const int s = (p - k + 11) % 11;   // compile-time
                    const float t = w6[k < 6 ? k : 10 - k];
                    acc[s][0] = fmaf(t, hf,  acc[s][0]);
                    acc[s][1] = fmaf(t, hi,  acc[s][1]);
                    acc[s][2] = fmaf(t, hv,  acc[s][2]);
                    acc[s][3] = fmaf(t, hff, acc[s][3]);
                    acc[s][4] = fmaf(t, hii, acc[s][4]);
                    acc[s][5] = fmaf(t, hvv, acc[s][5]);
                    acc[s][6] = fmaf(t, hfi, acc[s][6]);
                    acc[s][7] = fmaf(t, hfv, acc[s][7]);
                }
                // finalize output row r-10 (its slot just got its k=10 term)
                if (r >= 10) {
                    const int s = (p + 1) % 11;        // compile-time
                    const float mu1 = acc[s][0], mu2 = acc[s][1], mu3 = acc[s][2];
                    const float eff = acc[s][3], eii = acc[s][4], evv = acc[s][5];
                    const float efi = acc[s][6], efv = acc[s][7];
                    const float mu1sq = mu1*mu1, mu2sq = mu2*mu2, mu3sq = mu3*mu3;
                    const float mu12 = mu1*mu2, mu13 = mu1*mu3;
                    const float sf  = eff - mu1sq;
                    const float si  = eii - mu2sq;
                    const float sv  = evv - mu3sq;
                    const float s12 = efi - mu12;
                    const float s13 = efv - mu13;
                    const float n1 = (2.f*mu12 + SSIM_C1) * (2.f*s12 + SSIM_C2);
                    const float d1 = (mu1sq + mu2sq + SSIM_C1) * (sf + si + SSIM_C2);
                    const float n2 = (2.f*mu13 + SSIM_C1) * (2.f*s13 + SSIM_C2);
                    const float d2 = (mu1sq + mu3sq + SSIM_C1) * (sf + sv + SSIM_C2);
                    if (col_ok) lssim += n1/d1 + n2/d2;
                }
            }
        }
    }

    // cross-wave block reduction -> one partial write (no atomic)
#pragma unroll
    for (int off = 32; off > 0; off >>= 1)
        lssim += __shfl_down(lssim, off);
    __shared__ float red[4];
    if (lane == 0) red[wv] = lssim;
    __syncthreads();
    if (tid == 0) {
        const int blk = blockIdx.x + 2 * (blockIdx.y + 16 * blockIdx.z); // 0..1023
        part[blk] = red[0] + red[1] + red[2] + red[3];
    }
}

// ---------------- Kernel B: L1 + laplacian grad loss ------------------------
__device__ inline float4 lap3x3(const float* __restrict__ rm,
                                const float* __restrict__ rc,
                                const float* __restrict__ rp,
                                int x0, int xl, int xr, float4& center)
{
    float4 a = *(const float4*)(rm + x0);
    float4 b = *(const float4*)(rc + x0);
    float4 c = *(const float4*)(rp + x0);
    const float aL = rm[xl], bL = rc[xl], cL = rp[xl];
    const float aR = rm[xr], bR = rc[xr], cR = rp[xr];
    const float s0 = aL + bL + cL;
    const float s1 = a.x + b.x + c.x;
    const float s2 = a.y + b.y + c.y;
    const float s3 = a.z + b.z + c.z;
    const float s4 = a.w + b.w + c.w;
    const float s5 = aR + bR + cR;
    center = b;
    float4 l;
    l.x = (s0 + s1 + s2 - 9.f*b.x) * 0.0625f;
    l.y = (s1 + s2 + s3 - 9.f*b.y) * 0.0625f;
    l.z = (s2 + s3 + s4 - 9.f*b.z) * 0.0625f;
    l.w = (s3 + s4 + s5 - 9.f*b.w) * 0.0625f;
    return l;
}

// Grid: dim3(64, 32) = 2048 blocks; each block covers 8 rows of one batch
// image (4 iterations x 2 rows). Partial sums to d_ws, no atomics.
__global__ __launch_bounds__(256, 4)
void lapl1_kernel(const float* __restrict__ fus, const float* __restrict__ irp,
                  const float* __restrict__ vip, const float* __restrict__ mir,
                  const float* __restrict__ mvi,
                  float* __restrict__ part_l1, float* __restrict__ part_gr)
{
    const int b   = blockIdx.y;
    const int tid = threadIdx.x;
    const int xq  = tid & 127;
    const int x0  = xq * 4;
    const size_t ib = (size_t)b * 512 * 512;

    const int xl = (x0 == 0)        ? 1   : x0 - 1;   // reflect padding (x)
    const int xr = (x0 + 4 == 512)  ? 510 : x0 + 4;

    const float* Fb = fus + ib;
    const float* Ib = irp + ib;
    const float* Vb = vip + ib;

    float l1s = 0.f, grs = 0.f;

#pragma unroll
    for (int it = 0; it < 4; ++it) {
        const int y  = blockIdx.x * 8 + it * 2 + (tid >> 7);
        const int ym = (y == 0)   ? 1   : y - 1;       // reflect padding (y)
        const int yp = (y == 511) ? 510 : y + 1;

        float4 cf, ci, cv;
        const float4 lf = lap3x3(Fb + (size_t)ym*512, Fb + (size_t)y*512, Fb + (size_t)yp*512, x0, xl, xr, cf);
        const float4 li = lap3x3(Ib + (size_t)ym*512, Ib + (size_t)y*512, Ib + (size_t)yp*512, x0, xl, xr, ci);
        const float4 lv = lap3x3(Vb + (size_t)ym*512, Vb + (size_t)y*512, Vb + (size_t)yp*512, x0, xl, xr, cv);

        const float4 m1 = *(const float4*)(mir + ib + (size_t)y*512 + x0);
        const float4 m2 = *(const float4*)(mvi + ib + (size_t)y*512 + x0);

        l1s += fabsf(fmaxf(m1.x, m2.x) - cf.x) + fabsf(fmaxf(m1.y, m2.y) - cf.y)
             + fabsf(fmaxf(m1.z, m2.z) - cf.z) + fabsf(fmaxf(m1.w, m2.w) - cf.w);

        grs += fabsf(fmaxf(fabsf(li.x), fabsf(lv.x)) - fabsf(lf.x))
             + fabsf(fmaxf(fabsf(li.y), fabsf(lv.y)) - fabsf(lf.y))
             + fabsf(fmaxf(fabsf(li.z), fabsf(lv.z)) - fabsf(lf.z))
             + fabsf(fmaxf(fabsf(li.w), fabsf(lv.w)) - fabsf(lf.w));
    }

#pragma unroll
    for (int off = 32; off > 0; off >>= 1) {
        l1s += __shfl_down(l1s, off);
        grs += __shfl_down(grs, off);
    }
    __shared__ float red[8];
    if ((tid & 63) == 0) { red[tid >> 6] = l1s; red[4 + (tid >> 6)] = grs; }
    __syncthreads();
    if (tid == 0) {
        const int blk = blockIdx.x + 64 * blockIdx.y;  // 0..2047
        part_l1[blk] = red[0] + red[1] + red[2] + red[3];
        part_gr[blk] = red[4] + red[5] + red[6] + red[7];
    }
}

// ---------------- final combine: reduce all partials ------------------------
__global__ void final_kernel(const float* __restrict__ ws, float* __restrict__ out)
{
    const int tid = threadIdx.x;
    float s0 = 0.f, s1 = 0.f, s2 = 0.f;
#pragma unroll
    for (int i = tid; i < 1024; i += 256) s0 += ws[i];
#pragma unroll
    for (int i = tid; i < 2048; i += 256) {
        s1 += ws[1024 + i];
        s2 += ws[3072 + i];
    }
#pragma unroll
    for (int off = 32; off > 0; off >>= 1) {
        s0 += __shfl_down(s0, off);
        s1 += __shfl_down(s1, off);
        s2 += __shfl_down(s2, off);
    }
    __shared__ float red[12];
    if ((tid & 63) == 0) {
        red[tid >> 6] = s0; red[4 + (tid >> 6)] = s1; red[8 + (tid >> 6)] = s2;
    }
    __syncthreads();
    if (tid == 0) {
        const float ssim_sum = red[0] + red[1] + red[2] + red[3];
        const float l1_sum   = red[4] + red[5] + red[6] + red[7];
        const float gr_sum   = red[8] + red[9] + red[10] + red[11];
        const float ms = 2.f - ssim_sum / 8064128.f;   // 32*502*502
        const float l1 = l1_sum / 8388608.f;           // 32*512*512
        const float gr = gr_sum / 8388608.f;
        out[0] = ms + l1 + 10.f * gr;
    }
}

extern "C" void kernel_launch(void* const* d_in, const int* in_sizes, int n_in,
                              void* d_out, int out_size, void* d_ws, size_t ws_size,
                              hipStream_t stream)
{
    const float* fus = (const float*)d_in[0];
    const float* irp = (const float*)d_in[1];
    const float* vip = (const float*)d_in[2];
    const float* mir = (const float*)d_in[3];
    const float* mvi = (const float*)d_in[4];
    float* out = (float*)d_out;
    float* ws  = (float*)d_ws;

    // gaussian window (matches np: f64 normalize, cast to f32)
    GaussW gw;
    double g[11], s = 0.0;
    for (int i = 0; i < 11; ++i) {
        const double d = (double)i - 5.0;
        g[i] = std::exp(-(d * d) / (2.0 * 1.5 * 1.5));
        s += g[i];
    }
    for (int i = 0; i < 11; ++i) gw.w[i] = (float)(g[i] / s);

    ssim_kernel<<<dim3(2, 16, 32), 256, 0, stream>>>(fus, irp, vip, ws, gw);
    lapl1_kernel<<<dim3(64, 32), 256, 0, stream>>>(fus, irp, vip, mir, mvi,
                                                   ws + 1024, ws + 3072);
    final_kernel<<<1, 256, 0, stream>>>(ws, out);
}